// Round 4
// baseline (156.173 us; speedup 1.0000x reference)
//
#include <hip/hip_runtime.h>

// LSTM fused forward: B=131072, T=48, I=5, H=8, classes=2.
// MFMA formulation with hi/lo double-bf16 (round-3 numerics, verified):
//   A (16x32): k0-15 = W_hi (x cols 0-4, h cols 8-15), k16-31 = W_lo.
//   pass1: B = [B_hi | B_hi]; pass2: B = [B_lo | B_lo] accumulated.
// Per wave: 16 elems; lane owns units (2*grp, 2*grp+1) of elem (lane&15).
// Round-4 changes: single x LDS buffer (wave-private in-order DS), XOR bank
// swizzle on all x/h rows, v_cvt_pk_bf16_f32 packing, unified x/h addressing.

#define T 48
#define CH 8
#define NCH (T / CH)
#define EPW 16
#define WPB 2
#define EPB (EPW * WPB)
#define THREADS (64 * WPB)

typedef __attribute__((ext_vector_type(8))) short short8v;
typedef __attribute__((ext_vector_type(4))) float f32x4;
typedef __attribute__((ext_vector_type(4))) unsigned u32x4;

#if __has_builtin(__builtin_amdgcn_exp2f)
#define EXP2F(x) __builtin_amdgcn_exp2f(x)
#else
#define EXP2F(x) exp2f(x)
#endif
#if __has_builtin(__builtin_amdgcn_rcpf)
#define RCPF(x) __builtin_amdgcn_rcpf(x)
#else
#define RCPF(x) (1.0f / (x))
#endif

#define SCL_SIG  (-1.44269504f)   // sigmoid gates: e = 2^(scl*v)
#define SCL_TANH (-2.88539008f)   // tanh gates:    q = 2^(scl*v)

__device__ __forceinline__ unsigned short f2bf(float f) {
    unsigned u = __float_as_uint(f);
    return (unsigned short)((u + 0x7FFFu + ((u >> 16) & 1u)) >> 16);
}
__device__ __forceinline__ float bf2f(unsigned short b) {
    return __uint_as_float((unsigned)b << 16);
}
__device__ __forceinline__ unsigned cvt_pk_bf16(float a, float b) {
    unsigned r;
    asm("v_cvt_pk_bf16_f32 %0, %1, %2" : "=v"(r) : "v"(a), "v"(b));
    return r;   // lo16 = bf16(a), hi16 = bf16(b), RNE
}

// ei,ef,qg,eo are 2^(scaled pre-acts). i=1/(1+ei), f=1/(1+ef),
// g=(1-qg)/(1+qg), o=1/(1+eo); c'=f*c+i*g; h=o*tanh(c').
__device__ __forceinline__ void unitstep(float ei, float ef, float qg, float eo,
                                         float& c, float& h) {
    float Ai = 1.0f + ei, Af = 1.0f + ef, Ag = 1.0f + qg, Ao = 1.0f + eo;
    float P  = Ai * Ag;
    float R  = RCPF(P * Af);
    float num = fmaf(c, P, (2.0f - Ag) * Af);   // c*Ai*Ag + (1-qg)*Af
    c = num * R;                                // = f*c + i*g
    float qc = EXP2F(c * SCL_TANH);
    float Wc = 1.0f + qc;
    float Rh = RCPF(Wc * Ao);
    h = (2.0f - Wc) * Rh;                       // = tanh(c') * o
}

__global__ __launch_bounds__(THREADS, 6) void lstm_mfma(
    const float* __restrict__ x, const float* __restrict__ W_ih,
    const float* __restrict__ W_hh, const float* __restrict__ b_ih,
    const float* __restrict__ b_hh, const float* __restrict__ W_fc,
    const float* __restrict__ b_fc, float* __restrict__ out)
{
    // s_b[wv][plane hi/lo][row 0-7 = x t, row 8 = h][col 0-15][8 bf16]
    // plane stride 2304 B, row stride 256 B, col stride 16 B. 256-aligned so
    // XOR-64 on a byte offset toggles col-bit2 (the bank swizzle).
    __shared__ __align__(256) unsigned short s_b[WPB][2][9][EPW][8];
    __shared__ __align__(16) float s_wfc[T][4][4];

    const int tid  = threadIdx.x;
    const int wv   = tid >> 6;
    const int lane = tid & 63;
    const int e    = lane & 15;     // elem col (B/C) and A-row index
    const int grp  = lane >> 4;

    char* sbw = (char*)&s_b[wv][0][0][0][0];

    // ---- zero h rows (row 8, both planes) ----
    *(unsigned*)(sbw + 2048 + lane * 4) = 0u;
    *(unsigned*)(sbw + 2048 + 2304 + lane * 4) = 0u;

    // ---- stage W_fc rearranged: s_wfc[t][g][j] = W_fc[cls=j&1][t*8 + 2g+(j>>1)] ----
    for (int q = tid; q < T * 16; q += THREADS) {
        int t = q >> 4, g = (q >> 2) & 3, j = q & 3;
        int unit = 2 * g + (j >> 1), cls = j & 1;
        ((float*)s_wfc)[q] = W_fc[cls * (T * 8) + t * 8 + unit];
    }

    // ---- pack A fragments (hi in k0-15, lo in k16-31) + bias C-in ----
    const int au = e >> 1, ap = e & 1;
    const int row0 = ap * 8 + au;           // i (p=0) or f (p=1)
    const int row1 = 16 + ap * 8 + au;      // g (p=0) or o (p=1)
    const float sc1 = ap ? SCL_SIG : SCL_TANH;
    short8v A0, A1;
    #pragma unroll
    for (int j = 0; j < 8; ++j) {
        int k = grp * 8 + j;
        int kk = k & 15;
        float w0 = 0.f, w1 = 0.f;
        if (kk < 5)       { w0 = W_ih[row0 * 5 + kk] * SCL_SIG; w1 = W_ih[row1 * 5 + kk] * sc1; }
        else if (kk >= 8) { w0 = W_hh[row0 * 8 + kk - 8] * SCL_SIG; w1 = W_hh[row1 * 8 + kk - 8] * sc1; }
        unsigned short b0 = f2bf(w0), b1 = f2bf(w1);
        if (k >= 16) { b0 = f2bf(w0 - bf2f(b0)); b1 = f2bf(w1 - bf2f(b1)); }
        A0[j] = (short)b0; A1[j] = (short)b1;
    }
    f32x4 bias0, bias1;
    #pragma unroll
    for (int jj = 0; jj < 4; ++jj) {
        int rc = grp * 4 + jj;
        int uc = rc >> 1, pc = rc & 1;
        int w0r = pc * 8 + uc, w1r = 16 + pc * 8 + uc;
        bias0[jj] = (b_ih[w0r] + b_hh[w0r]) * SCL_SIG;
        bias1[jj] = (b_ih[w1r] + b_hh[w1r]) * (pc ? SCL_SIG : SCL_TANH);
    }

    // ---- x staging: lane stages elem (lane>>2), timesteps 2*(lane&3)+{0,1} ----
    const int es = lane >> 2;
    const int rr = lane & 3;
    const float* xbase = x + (size_t)(blockIdx.x * EPB + wv * EPW + es) * 240 + rr * 10;
    float xr[10];

    auto loadC = [&](int c) {
        const float2* p = (const float2*)(xbase + c * 40);
        #pragma unroll
        for (int q = 0; q < 5; ++q) { float2 v = p[q]; xr[2 * q] = v.x; xr[2 * q + 1] = v.y; }
    };
    auto writeC = [&]() {
        #pragma unroll
        for (int p2 = 0; p2 < 2; ++p2) {
            float x0 = xr[p2 * 5 + 0], x1 = xr[p2 * 5 + 1], x2 = xr[p2 * 5 + 2],
                  x3 = xr[p2 * 5 + 3], x4 = xr[p2 * 5 + 4];
            unsigned ph01 = cvt_pk_bf16(x0, x1);
            unsigned ph23 = cvt_pk_bf16(x2, x3);
            unsigned ph4  = cvt_pk_bf16(x4, 0.0f);
            float l0 = x0 - __uint_as_float(ph01 << 16);
            float l1 = x1 - __uint_as_float(ph01 & 0xFFFF0000u);
            float l2 = x2 - __uint_as_float(ph23 << 16);
            float l3 = x3 - __uint_as_float(ph23 & 0xFFFF0000u);
            float l4 = x4 - __uint_as_float(ph4 << 16);
            unsigned pl01 = cvt_pk_bf16(l0, l1);
            unsigned pl23 = cvt_pk_bf16(l2, l3);
            unsigned pl4  = cvt_pk_bf16(l4, 0.0f);
            int tl = 2 * rr + p2;
            int woff = tl * 256 + (es ^ ((tl & 2) << 1)) * 16;   // bank swizzle
            u32x4 hv = {ph01, ph23, ph4, 0u};
            u32x4 lv = {pl01, pl23, pl4, 0u};
            *(u32x4*)(sbw + woff) = hv;
            *(u32x4*)(sbw + woff + 2304) = lv;
        }
    };

    loadC(0);
    writeC();
    __syncthreads();    // s_wfc visibility (s_b is wave-private)

    const bool isX = (grp & 1) == 0;    // grp 0,2 read x rows; grp 1,3 read h row
    const int off0 = (isX ? 0 : 2048) + e * 16;   // byte offset in hi plane
    const int rstr = isX ? 256 : 0;
    const int hoff = 2048 + e * 16 + grp * 4;     // h write slot (hi plane)

    float c0 = 0.f, c1 = 0.f, h0, h1, acc0 = 0.f, acc1 = 0.f;

    #pragma unroll 1
    for (int c = 0; c < NCH; ++c) {
        if (c + 1 < NCH) loadC(c + 1);

        #pragma unroll
        for (int u = 0; u < CH; ++u) {
            int off = (off0 + u * rstr) ^ ((u & 2) << 5);   // col ^= 4 when u&2
            union { short8v v; u32x4 q; } bh, bl;
            bh.q = *(const u32x4*)(sbw + off);
            bl.q = *(const u32x4*)(sbw + off + 2304);

            f32x4 g0 = __builtin_amdgcn_mfma_f32_16x16x32_bf16(A0, bh.v, bias0, 0, 0, 0);
            f32x4 g1 = __builtin_amdgcn_mfma_f32_16x16x32_bf16(A1, bh.v, bias1, 0, 0, 0);
            g0 = __builtin_amdgcn_mfma_f32_16x16x32_bf16(A0, bl.v, g0, 0, 0, 0);
            g1 = __builtin_amdgcn_mfma_f32_16x16x32_bf16(A1, bl.v, g1, 0, 0, 0);

            unitstep(EXP2F(g0[0]), EXP2F(g0[1]), EXP2F(g1[0]), EXP2F(g1[1]), c0, h0);
            unitstep(EXP2F(g0[2]), EXP2F(g0[3]), EXP2F(g1[2]), EXP2F(g1[3]), c1, h1);

            // publish h (hi + lo) at next step's swizzled column
            unsigned pkh = cvt_pk_bf16(h0, h1);
            float hl0 = h0 - __uint_as_float(pkh << 16);
            float hl1 = h1 - __uint_as_float(pkh & 0xFFFF0000u);
            unsigned pkl = cvt_pk_bf16(hl0, hl1);
            int ho = hoff ^ (((u + 1) & 2) << 5);
            *(unsigned*)(sbw + ho) = pkh;
            *(unsigned*)(sbw + ho + 2304) = pkl;

            f32x4 wf = *(const f32x4*)&s_wfc[c * CH + u][grp][0];
            acc0 = fmaf(wf[0], h0, acc0);
            acc1 = fmaf(wf[1], h0, acc1);
            acc0 = fmaf(wf[2], h1, acc0);
            acc1 = fmaf(wf[3], h1, acc1);
        }

        if (c + 1 < NCH) writeC();
    }

    // ---- reduce FC partials across the 4 grps (lanes e, e+16, e+32, e+48) ----
    acc0 += __shfl_xor(acc0, 16); acc0 += __shfl_xor(acc0, 32);
    acc1 += __shfl_xor(acc1, 16); acc1 += __shfl_xor(acc1, 32);
    if (grp == 0) {
        int gb = blockIdx.x * EPB + wv * EPW + e;
        float2 o;
        o.x = acc0 + b_fc[0];
        o.y = acc1 + b_fc[1];
        *(float2*)&out[(size_t)gb * 2] = o;
    }
}

extern "C" void kernel_launch(void* const* d_in, const int* in_sizes, int n_in,
                              void* d_out, int out_size, void* d_ws, size_t ws_size,
                              hipStream_t stream) {
    const float* x    = (const float*)d_in[0];
    const float* W_ih = (const float*)d_in[1];
    const float* W_hh = (const float*)d_in[2];
    const float* b_ih = (const float*)d_in[3];
    const float* b_hh = (const float*)d_in[4];
    const float* W_fc = (const float*)d_in[5];
    const float* b_fc = (const float*)d_in[6];
    float* out = (float*)d_out;

    const int B = in_sizes[0] / 240;        // 131072
    dim3 grid(B / EPB), block(THREADS);
    lstm_mfma<<<grid, block, 0, stream>>>(x, W_ih, W_hh, b_ih, b_hh, W_fc, b_fc, out);
}

// Round 5
// 73.423 us; speedup vs baseline: 2.1270x; 2.1270x over previous
//
#include <hip/hip_runtime.h>

// LSTM fused forward: B=131072, T=48, I=5, H=8, classes=2.
// MFMA formulation with hi/lo double-bf16 (round-3 numerics, verified):
//   A (16x32): k0-15 = W_hi (x cols 0-4, h cols 8-15), k16-31 = W_lo.
//   pass1: B = [B_hi | B_hi]; pass2: B = [B_lo | B_lo] accumulated.
// Per wave: 16 elems; lane owns units (2*grp, 2*grp+1) of elem (lane&15).
// h feeds back via wave-private LDS rows (wave-lockstep, no barriers in loop).
// Round-5: single x LDS buffer (wave-private, in-order DS pipe => chunk c+1
// writes can't pass chunk c reads), u32x4 staging stores, cvt_pk_bf16 packing.
// NO __launch_bounds__ min-waves (round-4 lesson: it capped VGPR=40 -> spill).

#define T 48
#define CH 8
#define NCH (T / CH)
#define EPW 16
#define WPB 2
#define EPB (EPW * WPB)
#define THREADS (64 * WPB)

typedef __attribute__((ext_vector_type(8))) short short8v;
typedef __attribute__((ext_vector_type(4))) float f32x4;
typedef __attribute__((ext_vector_type(4))) unsigned u32x4;

#if __has_builtin(__builtin_amdgcn_exp2f)
#define EXP2F(x) __builtin_amdgcn_exp2f(x)
#else
#define EXP2F(x) exp2f(x)
#endif
#if __has_builtin(__builtin_amdgcn_rcpf)
#define RCPF(x) __builtin_amdgcn_rcpf(x)
#else
#define RCPF(x) (1.0f / (x))
#endif

#define SCL_SIG  (-1.44269504f)   // sigmoid gates: e = 2^(scl*v)
#define SCL_TANH (-2.88539008f)   // tanh gates:    q = 2^(scl*v)

__device__ __forceinline__ unsigned short f2bf(float f) {
    unsigned u = __float_as_uint(f);
    return (unsigned short)((u + 0x7FFFu + ((u >> 16) & 1u)) >> 16);
}
__device__ __forceinline__ float bf2f(unsigned short b) {
    return __uint_as_float((unsigned)b << 16);
}
__device__ __forceinline__ unsigned cvt_pk_bf16(float a, float b) {
    unsigned r;
    asm("v_cvt_pk_bf16_f32 %0, %1, %2" : "=v"(r) : "v"(a), "v"(b));
    return r;   // lo16 = bf16(a), hi16 = bf16(b), RNE
}

// ei,ef,qg,eo are 2^(scaled pre-acts). i=1/(1+ei), f=1/(1+ef),
// g=(1-qg)/(1+qg), o=1/(1+eo); c'=f*c+i*g; h=o*tanh(c').
__device__ __forceinline__ void unitstep(float ei, float ef, float qg, float eo,
                                         float& c, float& h) {
    float Ai = 1.0f + ei, Af = 1.0f + ef, Ag = 1.0f + qg, Ao = 1.0f + eo;
    float P  = Ai * Ag;
    float R  = RCPF(P * Af);
    float num = fmaf(c, P, (2.0f - Ag) * Af);   // c*Ai*Ag + (1-qg)*Af
    c = num * R;                                // = f*c + i*g
    float qc = EXP2F(c * SCL_TANH);
    float Wc = 1.0f + qc;
    float Rh = RCPF(Wc * Ao);
    h = (2.0f - Wc) * Rh;                       // = tanh(c') * o
}

__global__ __launch_bounds__(THREADS) void lstm_mfma(
    const float* __restrict__ x, const float* __restrict__ W_ih,
    const float* __restrict__ W_hh, const float* __restrict__ b_ih,
    const float* __restrict__ b_hh, const float* __restrict__ W_fc,
    const float* __restrict__ b_fc, float* __restrict__ out)
{
    __shared__ __align__(16) unsigned short s_xh[WPB][CH][EPW][8];
    __shared__ __align__(16) unsigned short s_xl[WPB][CH][EPW][8];
    __shared__ __align__(16) unsigned short s_hh[WPB][EPW][8];
    __shared__ __align__(16) unsigned short s_hl[WPB][EPW][8];
    __shared__ __align__(16) float s_wfc[T][4][4];

    const int tid  = threadIdx.x;
    const int wv   = tid >> 6;
    const int lane = tid & 63;
    const int e    = lane & 15;     // elem col (B/C) and A-row index
    const int grp  = lane >> 4;

    // ---- zero h rows ----
    ((unsigned*)&s_hh[wv][0][0])[lane] = 0u;
    ((unsigned*)&s_hl[wv][0][0])[lane] = 0u;

    // ---- stage W_fc rearranged: s_wfc[t][g][j] = W_fc[cls=j&1][t*8 + 2g+(j>>1)] ----
    for (int q = tid; q < T * 16; q += THREADS) {
        int t = q >> 4, g = (q >> 2) & 3, j = q & 3;
        int unit = 2 * g + (j >> 1), cls = j & 1;
        ((float*)s_wfc)[q] = W_fc[cls * (T * 8) + t * 8 + unit];
    }

    // ---- pack A fragments (hi in k0-15, lo in k16-31) + bias C-in ----
    const int au = e >> 1, ap = e & 1;
    const int row0 = ap * 8 + au;           // i (p=0) or f (p=1)
    const int row1 = 16 + ap * 8 + au;      // g (p=0) or o (p=1)
    const float sc1 = ap ? SCL_SIG : SCL_TANH;
    short8v A0, A1;
    #pragma unroll
    for (int j = 0; j < 8; ++j) {
        int k = grp * 8 + j;
        int kk = k & 15;
        float w0 = 0.f, w1 = 0.f;
        if (kk < 5)       { w0 = W_ih[row0 * 5 + kk] * SCL_SIG; w1 = W_ih[row1 * 5 + kk] * sc1; }
        else if (kk >= 8) { w0 = W_hh[row0 * 8 + kk - 8] * SCL_SIG; w1 = W_hh[row1 * 8 + kk - 8] * sc1; }
        unsigned short b0 = f2bf(w0), b1 = f2bf(w1);
        if (k >= 16) { b0 = f2bf(w0 - bf2f(b0)); b1 = f2bf(w1 - bf2f(b1)); }
        A0[j] = (short)b0; A1[j] = (short)b1;
    }
    f32x4 bias0, bias1;
    #pragma unroll
    for (int jj = 0; jj < 4; ++jj) {
        int rc = grp * 4 + jj;
        int uc = rc >> 1, pc = rc & 1;
        int w0r = pc * 8 + uc, w1r = 16 + pc * 8 + uc;
        bias0[jj] = (b_ih[w0r] + b_hh[w0r]) * SCL_SIG;
        bias1[jj] = (b_ih[w1r] + b_hh[w1r]) * (pc ? SCL_SIG : SCL_TANH);
    }

    // ---- x staging: lane stages elem (lane>>2), timesteps 2*(lane&3)+{0,1} ----
    const int es = lane >> 2;
    const int rr = lane & 3;
    const float* xbase = x + (size_t)(blockIdx.x * EPB + wv * EPW + es) * 240 + rr * 10;
    float xr[10];

    auto loadC = [&](int c) {
        const float2* p = (const float2*)(xbase + c * 40);
        #pragma unroll
        for (int q = 0; q < 5; ++q) { float2 v = p[q]; xr[2 * q] = v.x; xr[2 * q + 1] = v.y; }
    };
    auto writeC = [&]() {
        #pragma unroll
        for (int p2 = 0; p2 < 2; ++p2) {
            float x0 = xr[p2 * 5 + 0], x1 = xr[p2 * 5 + 1], x2 = xr[p2 * 5 + 2],
                  x3 = xr[p2 * 5 + 3], x4 = xr[p2 * 5 + 4];
            unsigned ph01 = cvt_pk_bf16(x0, x1);
            unsigned ph23 = cvt_pk_bf16(x2, x3);
            unsigned ph4  = cvt_pk_bf16(x4, 0.0f);
            float l0 = x0 - __uint_as_float(ph01 << 16);
            float l1 = x1 - __uint_as_float(ph01 & 0xFFFF0000u);
            float l2 = x2 - __uint_as_float(ph23 << 16);
            float l3 = x3 - __uint_as_float(ph23 & 0xFFFF0000u);
            float l4 = x4 - __uint_as_float(ph4 << 16);
            unsigned pl01 = cvt_pk_bf16(l0, l1);
            unsigned pl23 = cvt_pk_bf16(l2, l3);
            unsigned pl4  = cvt_pk_bf16(l4, 0.0f);
            int tl = 2 * rr + p2;
            u32x4 hv = {ph01, ph23, ph4, 0u};
            u32x4 lv = {pl01, pl23, pl4, 0u};
            *(u32x4*)&s_xh[wv][tl][es][0] = hv;
            *(u32x4*)&s_xl[wv][tl][es][0] = lv;
        }
    };

    loadC(0);
    writeC();
    __syncthreads();    // s_wfc visibility (x/h rows are wave-private)

    // ---- loop-invariant fragment pointers ----
    const bool isX = (grp & 1) == 0;    // grp 0,2 read x rows; grp 1,3 read h row
    const unsigned short* pH0;
    const unsigned short* pL0;
    int stepB;
    if (isX) { pH0 = &s_xh[wv][0][e][0]; pL0 = &s_xl[wv][0][e][0]; stepB = EPW * 8; }
    else     { pH0 = &s_hh[wv][e][0];    pL0 = &s_hl[wv][e][0];    stepB = 0; }
    unsigned* hwpH = (unsigned*)&s_hh[wv][e][2 * grp];
    unsigned* hwpL = (unsigned*)&s_hl[wv][e][2 * grp];

    float c0 = 0.f, c1 = 0.f, h0, h1, acc0 = 0.f, acc1 = 0.f;

    #pragma unroll 1
    for (int c = 0; c < NCH; ++c) {
        if (c + 1 < NCH) loadC(c + 1);
        const unsigned short* pH = pH0;
        const unsigned short* pL = pL0;

        #pragma unroll
        for (int u = 0; u < CH; ++u) {
            union { short8v v; u32x4 q; } bh, bl;
            bh.q = *(const u32x4*)pH;
            bl.q = *(const u32x4*)pL;

            f32x4 g0 = __builtin_amdgcn_mfma_f32_16x16x32_bf16(A0, bh.v, bias0, 0, 0, 0);
            f32x4 g1 = __builtin_amdgcn_mfma_f32_16x16x32_bf16(A1, bh.v, bias1, 0, 0, 0);
            g0 = __builtin_amdgcn_mfma_f32_16x16x32_bf16(A0, bl.v, g0, 0, 0, 0);
            g1 = __builtin_amdgcn_mfma_f32_16x16x32_bf16(A1, bl.v, g1, 0, 0, 0);

            unitstep(EXP2F(g0[0]), EXP2F(g0[1]), EXP2F(g1[0]), EXP2F(g1[1]), c0, h0);
            unitstep(EXP2F(g0[2]), EXP2F(g0[3]), EXP2F(g1[2]), EXP2F(g1[3]), c1, h1);

            // publish h (hi + lo) for next step's B-frags
            unsigned pkh = cvt_pk_bf16(h0, h1);
            float hl0 = h0 - __uint_as_float(pkh << 16);
            float hl1 = h1 - __uint_as_float(pkh & 0xFFFF0000u);
            unsigned pkl = cvt_pk_bf16(hl0, hl1);
            *hwpH = pkh;
            *hwpL = pkl;

            f32x4 wf = *(const f32x4*)&s_wfc[c * CH + u][grp][0];
            acc0 = fmaf(wf[0], h0, acc0);
            acc1 = fmaf(wf[1], h0, acc1);
            acc0 = fmaf(wf[2], h1, acc0);
            acc1 = fmaf(wf[3], h1, acc1);

            pH += stepB; pL += stepB;
        }
        if (c + 1 < NCH) writeC();
    }

    // ---- reduce FC partials across the 4 grps (lanes e, e+16, e+32, e+48) ----
    acc0 += __shfl_xor(acc0, 16); acc0 += __shfl_xor(acc0, 32);
    acc1 += __shfl_xor(acc1, 16); acc1 += __shfl_xor(acc1, 32);
    if (grp == 0) {
        int gb = blockIdx.x * EPB + wv * EPW + e;
        float2 o;
        o.x = acc0 + b_fc[0];
        o.y = acc1 + b_fc[1];
        *(float2*)&out[(size_t)gb * 2] = o;
    }
}

extern "C" void kernel_launch(void* const* d_in, const int* in_sizes, int n_in,
                              void* d_out, int out_size, void* d_ws, size_t ws_size,
                              hipStream_t stream) {
    const float* x    = (const float*)d_in[0];
    const float* W_ih = (const float*)d_in[1];
    const float* W_hh = (const float*)d_in[2];
    const float* b_ih = (const float*)d_in[3];
    const float* b_hh = (const float*)d_in[4];
    const float* W_fc = (const float*)d_in[5];
    const float* b_fc = (const float*)d_in[6];
    float* out = (float*)d_out;

    const int B = in_sizes[0] / 240;        // 131072
    dim3 grid(B / EPB), block(THREADS);
    lstm_mfma<<<grid, block, 0, stream>>>(x, W_ih, W_hh, b_ih, b_hh, W_fc, b_fc, out);
}